// Round 1
// baseline (174.099 us; speedup 1.0000x reference)
//
#include <hip/hip_runtime.h>

typedef __attribute__((ext_vector_type(8))) short short8;
typedef __attribute__((ext_vector_type(4))) float floatx4;
typedef unsigned int uint;
typedef unsigned short ushort;
typedef __attribute__((ext_vector_type(4))) uint uintx4;

#define NTOK   8192
#define DIN    1024
#define DOUT   1024
#define NJ     96        // 84 decision nodes (12 trees x 7) + 12 gates
#define TOKPB  32        // tokens per block (k_routed) -> 256 blocks
#define XSTR   136       // LDS row stride (bf16 elems): rows 16B-aligned, 2-way max conflict
#define DSTR   97        // decis LDS row stride (f32)
#define SSTR   85        // sdec LDS row stride (f32)
#define LOT_H  (DOUT * NJ)

static __device__ inline ushort f2b(float f) {
    uint u = __builtin_bit_cast(uint, f);
    u = u + 0x7fffu + ((u >> 16) & 1u);   // RNE
    return (ushort)(u >> 16);
}
static __device__ inline uint pack2(float a, float b) {
    return (uint)f2b(a) | ((uint)f2b(b) << 16);
}

// ---------------------------------------------------------------------------
// k_prep: f32 -> bf16.  lo [3][96][1024] -> lot [3][1024][96] (transposed);
// dw[84][1024] ++ gw[12][1024] -> wcat[96][1024].
// ---------------------------------------------------------------------------
__global__ __launch_bounds__(256) void k_prep(const float* __restrict__ lo,
                                              const float* __restrict__ dw,
                                              const float* __restrict__ gw,
                                              ushort* __restrict__ lot,
                                              ushort* __restrict__ wcat) {
    int i = blockIdx.x * 256 + threadIdx.x;
    if (i < 3 * LOT_H) {
        int h = i / LOT_H;
        int rem = i - h * LOT_H;
        int k = rem >> 10;
        int d = rem & 1023;
        lot[h * LOT_H + d * NJ + k] = f2b(lo[i]);
    } else {
        int j = i - 3 * LOT_H;
        int r = j >> 10, c = j & 1023;
        float v = (r < 84) ? dw[r * DIN + c] : gw[(r - 84) * DIN + c];
        wcat[j] = f2b(v);
    }
}

// ---------------------------------------------------------------------------
// k_routed: decisions+gates GEMM (MFMA bf16) + routing epilogue
//   -> routed[8192][96] bf16.  32 tokens/block, 256 blocks (1 block/CU).
// Register-prefetch pipeline: iteration k+1's global loads are issued right
// after the stage barrier, hiding load latency under ds_read+MFMA (we only
// have 1 wave/SIMD, so TLP cannot hide it).
// x loads are non-temporal (stream-once) to avoid evicting wcat from L2.
// ---------------------------------------------------------------------------
__global__ __launch_bounds__(256) void k_routed(
    const float* __restrict__ x,     // [8192][1024] f32
    const ushort* __restrict__ wcat, // [96][1024] bf16
    const float* __restrict__ db,    // [84]
    const float* __restrict__ ntl,   // [84]
    const float* __restrict__ gb,    // [12]
    const int*   __restrict__ pi,    // [8][3]
    const float* __restrict__ pd,    // [8][3]
    ushort* __restrict__ routed)     // [8192][96]
{
    __shared__ __attribute__((aligned(16))) char smem[34816];
    __shared__ float invt[84];
    __shared__ float biasf[96];
    __shared__ int   pis[24];
    __shared__ float pds[24];

    ushort* xl = (ushort*)smem;                 // [32][XSTR] bf16
    ushort* wl = (ushort*)(smem + TOKPB * XSTR * 2);   // [96][XSTR] bf16
    float*  decis = (float*)smem;               // [32][DSTR] f32 (reuse)
    float*  sdecs = (float*)(smem + TOKPB * DSTR * 4); // [32][SSTR] f32

    const int tid = threadIdx.x;
    const int tb  = blockIdx.x * TOKPB;

    if (tid < 84) {
        float z = ntl[tid] + 0.5413f;
        float sp = (z > 20.0f) ? z : log1pf(__expf(z));   // softplus
        invt[tid]  = 1.0f / sp;
        biasf[tid] = db[tid];
    } else if (tid < 96) {
        biasf[tid] = gb[tid - 84];
    } else if (tid < 120) {
        pis[tid - 96] = pi[tid - 96];
    } else if (tid < 144) {
        pds[tid - 120] = pd[tid - 120];
    }

    const int wave = tid >> 6, lane = tid & 63;
    const int lrow = lane & 15, quad = lane >> 4;
    const int wm = wave & 1, wn = wave >> 1;

    floatx4 acc[3];
#pragma unroll
    for (int nt = 0; nt < 3; ++nt) acc[nt] = (floatx4)(0.0f);

    // register double-buffers for staged tiles
    floatx4 xv[2][4];
    uintx4  wv[2][6];

#define LOADX(B, KC) do { \
    _Pragma("unroll") for (int i_ = 0; i_ < 4; ++i_) { \
        int idx_ = tid + 256 * i_; \
        int r_ = idx_ >> 5, c_ = idx_ & 31; \
        xv[B][i_] = __builtin_nontemporal_load( \
            (const floatx4*)(x + (size_t)(tb + r_) * DIN + (KC) * 128 + c_ * 4)); \
    } } while (0)

#define LOADW(B, KC) do { \
    _Pragma("unroll") for (int i_ = 0; i_ < 6; ++i_) { \
        int idx_ = tid + 256 * i_; \
        int r_ = idx_ >> 4, c_ = idx_ & 15; \
        wv[B][i_] = *(const uintx4*)(wcat + r_ * DIN + (KC) * 128 + c_ * 8); \
    } } while (0)

#define STAGE(B) do { \
    _Pragma("unroll") for (int i_ = 0; i_ < 4; ++i_) { \
        int idx_ = tid + 256 * i_; \
        int r_ = idx_ >> 5, c_ = idx_ & 31; \
        uint2 p_; \
        p_.x = pack2(xv[B][i_][0], xv[B][i_][1]); \
        p_.y = pack2(xv[B][i_][2], xv[B][i_][3]); \
        *(uint2*)(xl + r_ * XSTR + c_ * 4) = p_; \
    } \
    _Pragma("unroll") for (int i_ = 0; i_ < 6; ++i_) { \
        int idx_ = tid + 256 * i_; \
        int r_ = idx_ >> 4, c_ = idx_ & 15; \
        *(uintx4*)(wl + r_ * XSTR + c_ * 8) = wv[B][i_]; \
    } } while (0)

    LOADX(0, 0);
    LOADW(0, 0);

#pragma unroll
    for (int kc = 0; kc < 8; ++kc) {
        const int cur = kc & 1, nxt = cur ^ 1;
        __syncthreads();            // previous iter's ds_reads complete
        STAGE(cur);
        __syncthreads();
        if (kc < 7) {               // issue next tile's loads early
            LOADX(nxt, kc + 1);
            LOADW(nxt, kc + 1);
        }

        short8 a[4];
#pragma unroll
        for (int kt = 0; kt < 4; ++kt)
            a[kt] = *(const short8*)(xl + (wm * 16 + lrow) * XSTR + kt * 32 + quad * 8);
#pragma unroll
        for (int nt = 0; nt < 3; ++nt) {
#pragma unroll
            for (int kt = 0; kt < 4; ++kt) {
                short8 b = *(const short8*)(wl + (wn * 48 + nt * 16 + lrow) * XSTR + kt * 32 + quad * 8);
                acc[nt] = __builtin_amdgcn_mfma_f32_16x16x32_bf16(a[kt], b, acc[nt], 0, 0, 0);
            }
        }
    }
#undef LOADX
#undef LOADW
#undef STAGE

    __syncthreads();
    // C/D: col = lane&15 (j within 16-tile), row = quad*4+reg (token)
#pragma unroll
    for (int nt = 0; nt < 3; ++nt)
#pragma unroll
        for (int r = 0; r < 4; ++r)
            decis[(wm * 16 + quad * 4 + r) * DSTR + wn * 48 + nt * 16 + lrow] = acc[nt][r];
    __syncthreads();

    // stage 1: sigmoid over 32 tokens x 84 nodes = 2688
#pragma unroll
    for (int i = 0; i < 11; ++i) {
        int idx = tid + 256 * i;
        if (idx < TOKPB * 84) {
            int tk = idx / 84, nd = idx - tk * 84;
            float dv = (decis[tk * DSTR + nd] + biasf[nd]) * invt[nd];
            sdecs[tk * SSTR + nd] = 1.0f / (1.0f + __expf(-dv));
        }
    }
    __syncthreads();

    // stage 2: 256 threads = 32 tokens x 8 leaves
    {
        const int tk = tid >> 3, l = tid & 7;
        float g[12], gm = -1e30f;
#pragma unroll
        for (int tt = 0; tt < 12; ++tt) {
            g[tt] = decis[tk * DSTR + 84 + tt] + biasf[84 + tt];
            gm = fmaxf(gm, g[tt]);
        }
        float gs = 0.0f;
#pragma unroll
        for (int tt = 0; tt < 12; ++tt) { g[tt] = __expf(g[tt] - gm); gs += g[tt]; }
        float ginv = 1.0f / gs;

        const int   n0 = pis[l * 3 + 0], n1 = pis[l * 3 + 1], n2 = pis[l * 3 + 2];
        const float d0 = pds[l * 3 + 0], d1 = pds[l * 3 + 1], d2 = pds[l * 3 + 2];
        const float* sd = sdecs + tk * SSTR;
        ushort* dst = routed + (size_t)(tb + tk) * NJ + l;
#pragma unroll
        for (int t = 0; t < 12; ++t) {
            float s0 = sd[t * 7 + n0], s1 = sd[t * 7 + n1], s2 = sd[t * 7 + n2];
            float pb = g[t] * ginv
                     * (d0 * s0 + (1.0f - d0) * (1.0f - s0))
                     * (d1 * s1 + (1.0f - d1) * (1.0f - s1))
                     * (d2 * s2 + (1.0f - d2) * (1.0f - s2));
            dst[t * 8] = f2b(pb);
        }
    }
}

// ---------------------------------------------------------------------------
// k_out: out[h][tok][d] = sum_k routed[tok][k] * lot[h][d][k]  (MFMA, K=96)
// OUTPUT f32, NON-TEMPORAL stores: the 100.7 MB f32 write stream must not
// sweep L2 (it evicts routed/lot which every block re-reads).
// 64 tokens x 128 d per block. grid: (128 token tiles, 8 d tiles, 3 heads).
// ---------------------------------------------------------------------------
__global__ __launch_bounds__(256) void k_out(
    const ushort* __restrict__ routed,  // [8192][96] bf16
    const ushort* __restrict__ lot,     // [3][1024][96] bf16
    float* __restrict__ out)            // [3][8192][1024] f32
{
    const int tb = blockIdx.x * 64;
    const int d0 = blockIdx.y * 128;
    const int h  = blockIdx.z;
    const int wave = threadIdx.x >> 6, lane = threadIdx.x & 63;
    const int lrow = lane & 15, quad = lane >> 4;

    const ushort* ap = routed + (size_t)(tb + wave * 16 + lrow) * NJ + quad * 8;
    short8 a[3];
#pragma unroll
    for (int kk = 0; kk < 3; ++kk) a[kk] = *(const short8*)(ap + kk * 32);

    const ushort* bp = lot + (size_t)h * LOT_H + (size_t)(d0 + lrow) * NJ + quad * 8;
    floatx4 acc[8];
#pragma unroll
    for (int nt = 0; nt < 8; ++nt) {
        acc[nt] = (floatx4)(0.0f);
#pragma unroll
        for (int kk = 0; kk < 3; ++kk) {
            short8 b = *(const short8*)(bp + nt * 16 * NJ + kk * 32);
            acc[nt] = __builtin_amdgcn_mfma_f32_16x16x32_bf16(a[kk], b, acc[nt], 0, 0, 0);
        }
    }
#pragma unroll
    for (int nt = 0; nt < 8; ++nt) {
        int d = d0 + nt * 16 + lrow;
#pragma unroll
        for (int r = 0; r < 4; ++r) {
            int tok = tb + wave * 16 + quad * 4 + r;
            __builtin_nontemporal_store(acc[nt][r],
                out + ((size_t)h * NTOK + tok) * DOUT + d);
        }
    }
}

// ---------------------------------------------------------------------------
extern "C" void kernel_launch(void* const* d_in, const int* in_sizes, int n_in,
                              void* d_out, int out_size, void* d_ws, size_t ws_size,
                              hipStream_t stream) {
    const float* x   = (const float*)d_in[0];
    const float* dw  = (const float*)d_in[1];
    const float* db  = (const float*)d_in[2];
    const float* ntl = (const float*)d_in[3];
    const float* gw  = (const float*)d_in[4];
    const float* gb  = (const float*)d_in[5];
    const float* lo  = (const float*)d_in[6];
    const int*   pi  = (const int*)d_in[7];
    const float* pd  = (const float*)d_in[8];
    float* out = (float*)d_out;

    ushort* routed = (ushort*)d_ws;                    // 8192*96*2  = 1.57 MB
    ushort* lot    = routed + (size_t)NTOK * NJ;       // 3*98304*2  = 0.59 MB
    ushort* wcat   = lot + (size_t)3 * LOT_H;          // 96*1024*2  = 0.20 MB

    k_prep<<<dim3((3 * LOT_H + NJ * DIN) / 256), dim3(256), 0, stream>>>(lo, dw, gw, lot, wcat);
    k_routed<<<dim3(NTOK / TOKPB), dim3(256), 0, stream>>>(x, wcat, db, ntl, gb, pi, pd, routed);
    k_out<<<dim3(NTOK / 64, DOUT / 128, 3), dim3(256), 0, stream>>>(routed, lot, out);
}

// Round 2
// 161.091 us; speedup vs baseline: 1.0808x; 1.0808x over previous
//
#include <hip/hip_runtime.h>

typedef __attribute__((ext_vector_type(8))) short short8;
typedef __attribute__((ext_vector_type(4))) float floatx4;
typedef unsigned int uint;
typedef unsigned short ushort;
typedef __attribute__((ext_vector_type(4))) uint uintx4;

#define NTOK   8192
#define DIN    1024
#define DOUT   1024
#define NJ     96        // 84 decision nodes (12 trees x 7) + 12 gates
#define TOKPB  32        // tokens per block -> 256 blocks (1/CU)
#define XSTR   136       // LDS row stride (bf16 elems) for x/w tiles
#define DSTR   97        // decis LDS row stride (f32)
#define SSTR   85        // sdec LDS row stride (f32)
#define RSTR   104       // routed LDS tile row stride (bf16): 208 B, 16B-aligned
#define LOT_H  (DOUT * NJ)

static __device__ inline ushort f2b(float f) {
    uint u = __builtin_bit_cast(uint, f);
    u = u + 0x7fffu + ((u >> 16) & 1u);   // RNE
    return (ushort)(u >> 16);
}
static __device__ inline uint pack2(float a, float b) {
    return (uint)f2b(a) | ((uint)f2b(b) << 16);
}

// ---------------------------------------------------------------------------
// k_prep: f32 -> bf16.  lo [3][96][1024] -> lot [3][1024][96] (transposed);
// dw[84][1024] ++ gw[12][1024] -> wcat[96][1024].
// ---------------------------------------------------------------------------
__global__ __launch_bounds__(256) void k_prep(const float* __restrict__ lo,
                                              const float* __restrict__ dw,
                                              const float* __restrict__ gw,
                                              ushort* __restrict__ lot,
                                              ushort* __restrict__ wcat) {
    int i = blockIdx.x * 256 + threadIdx.x;
    if (i < 3 * LOT_H) {
        int h = i / LOT_H;
        int rem = i - h * LOT_H;
        int k = rem >> 10;
        int d = rem & 1023;
        lot[h * LOT_H + d * NJ + k] = f2b(lo[i]);
    } else {
        int j = i - 3 * LOT_H;
        int r = j >> 10, c = j & 1023;
        float v = (r < 84) ? dw[r * DIN + c] : gw[(r - 84) * DIN + c];
        wcat[j] = f2b(v);
    }
}

// ---------------------------------------------------------------------------
// k_fused: per block of 32 tokens:
//   phase 1: decisions+gates GEMM (MFMA bf16, K=1024) + routing epilogue
//            -> routed tile [32][96] bf16 kept in LDS (no global round-trip)
//   phase 2: out GEMM: out[h][tok][d] = sum_k rt[tok][k] * lot[h][d][k]
//            M=32, N=3072 (3 heads x 1024), K=96; non-temporal f32 stores
//            (the 96 MiB write stream must not sweep L2 -> lot stays hot).
// ---------------------------------------------------------------------------
__global__ __launch_bounds__(256) void k_fused(
    const float* __restrict__ x,     // [8192][1024] f32
    const ushort* __restrict__ wcat, // [96][1024] bf16
    const float* __restrict__ db,    // [84]
    const float* __restrict__ ntl,   // [84]
    const float* __restrict__ gb,    // [12]
    const int*   __restrict__ pi,    // [8][3]
    const float* __restrict__ pd,    // [8][3]
    const ushort* __restrict__ lot,  // [3][1024][96] bf16
    float* __restrict__ out)         // [3][8192][1024] f32
{
    __shared__ __attribute__((aligned(16))) char smem[34816];
    __shared__ __attribute__((aligned(16))) ushort rt[TOKPB][RSTR];
    __shared__ float invt[84];
    __shared__ float biasf[96];
    __shared__ int   pis[24];
    __shared__ float pds[24];

    ushort* xl = (ushort*)smem;                        // [32][XSTR] bf16
    ushort* wl = (ushort*)(smem + TOKPB * XSTR * 2);   // [96][XSTR] bf16
    float*  decis = (float*)smem;                      // [32][DSTR] f32 (reuse)
    float*  sdecs = (float*)(smem + TOKPB * DSTR * 4); // [32][SSTR] f32

    const int tid = threadIdx.x;
    const int tb  = blockIdx.x * TOKPB;

    if (tid < 84) {
        float z = ntl[tid] + 0.5413f;
        float sp = (z > 20.0f) ? z : log1pf(__expf(z));   // softplus
        invt[tid]  = 1.0f / sp;
        biasf[tid] = db[tid];
    } else if (tid < 96) {
        biasf[tid] = gb[tid - 84];
    } else if (tid < 120) {
        pis[tid - 96] = pi[tid - 96];
    } else if (tid < 144) {
        pds[tid - 120] = pd[tid - 120];
    }

    const int wave = tid >> 6, lane = tid & 63;
    const int lrow = lane & 15, quad = lane >> 4;
    const int wm = wave & 1, wn = wave >> 1;

    floatx4 acc[3];
#pragma unroll
    for (int nt = 0; nt < 3; ++nt) acc[nt] = (floatx4)(0.0f);

    // register double-buffers for staged tiles
    floatx4 xv[2][4];
    uintx4  wv[2][6];

#define LOADX(B, KC) do { \
    _Pragma("unroll") for (int i_ = 0; i_ < 4; ++i_) { \
        int idx_ = tid + 256 * i_; \
        int r_ = idx_ >> 5, c_ = idx_ & 31; \
        xv[B][i_] = __builtin_nontemporal_load( \
            (const floatx4*)(x + (size_t)(tb + r_) * DIN + (KC) * 128 + c_ * 4)); \
    } } while (0)

#define LOADW(B, KC) do { \
    _Pragma("unroll") for (int i_ = 0; i_ < 6; ++i_) { \
        int idx_ = tid + 256 * i_; \
        int r_ = idx_ >> 4, c_ = idx_ & 15; \
        wv[B][i_] = *(const uintx4*)(wcat + r_ * DIN + (KC) * 128 + c_ * 8); \
    } } while (0)

#define STAGE(B) do { \
    _Pragma("unroll") for (int i_ = 0; i_ < 4; ++i_) { \
        int idx_ = tid + 256 * i_; \
        int r_ = idx_ >> 5, c_ = idx_ & 31; \
        uint2 p_; \
        p_.x = pack2(xv[B][i_][0], xv[B][i_][1]); \
        p_.y = pack2(xv[B][i_][2], xv[B][i_][3]); \
        *(uint2*)(xl + r_ * XSTR + c_ * 4) = p_; \
    } \
    _Pragma("unroll") for (int i_ = 0; i_ < 6; ++i_) { \
        int idx_ = tid + 256 * i_; \
        int r_ = idx_ >> 4, c_ = idx_ & 15; \
        *(uintx4*)(wl + r_ * XSTR + c_ * 8) = wv[B][i_]; \
    } } while (0)

    LOADX(0, 0);
    LOADW(0, 0);

#pragma unroll
    for (int kc = 0; kc < 8; ++kc) {
        const int cur = kc & 1, nxt = cur ^ 1;
        __syncthreads();            // previous iter's ds_reads complete
        STAGE(cur);
        __syncthreads();
        if (kc < 7) {               // issue next tile's loads early
            LOADX(nxt, kc + 1);
            LOADW(nxt, kc + 1);
        }

        short8 a[4];
#pragma unroll
        for (int kt = 0; kt < 4; ++kt)
            a[kt] = *(const short8*)(xl + (wm * 16 + lrow) * XSTR + kt * 32 + quad * 8);
#pragma unroll
        for (int nt = 0; nt < 3; ++nt) {
#pragma unroll
            for (int kt = 0; kt < 4; ++kt) {
                short8 b = *(const short8*)(wl + (wn * 48 + nt * 16 + lrow) * XSTR + kt * 32 + quad * 8);
                acc[nt] = __builtin_amdgcn_mfma_f32_16x16x32_bf16(a[kt], b, acc[nt], 0, 0, 0);
            }
        }
    }
#undef LOADX
#undef LOADW
#undef STAGE

    __syncthreads();
    // C/D: col = lane&15 (j within 16-tile), row = quad*4+reg (token)
#pragma unroll
    for (int nt = 0; nt < 3; ++nt)
#pragma unroll
        for (int r = 0; r < 4; ++r)
            decis[(wm * 16 + quad * 4 + r) * DSTR + wn * 48 + nt * 16 + lrow] = acc[nt][r];
    __syncthreads();

    // stage 1: sigmoid over 32 tokens x 84 nodes = 2688
#pragma unroll
    for (int i = 0; i < 11; ++i) {
        int idx = tid + 256 * i;
        if (idx < TOKPB * 84) {
            int tk = idx / 84, nd = idx - tk * 84;
            float dv = (decis[tk * DSTR + nd] + biasf[nd]) * invt[nd];
            sdecs[tk * SSTR + nd] = 1.0f / (1.0f + __expf(-dv));
        }
    }
    __syncthreads();

    // stage 2: 256 threads = 32 tokens x 8 leaves -> routed tile in LDS
    {
        const int tk = tid >> 3, l = tid & 7;
        float g[12], gm = -1e30f;
#pragma unroll
        for (int tt = 0; tt < 12; ++tt) {
            g[tt] = decis[tk * DSTR + 84 + tt] + biasf[84 + tt];
            gm = fmaxf(gm, g[tt]);
        }
        float gs = 0.0f;
#pragma unroll
        for (int tt = 0; tt < 12; ++tt) { g[tt] = __expf(g[tt] - gm); gs += g[tt]; }
        float ginv = 1.0f / gs;

        const int   n0 = pis[l * 3 + 0], n1 = pis[l * 3 + 1], n2 = pis[l * 3 + 2];
        const float d0 = pds[l * 3 + 0], d1 = pds[l * 3 + 1], d2 = pds[l * 3 + 2];
        const float* sd = sdecs + tk * SSTR;
#pragma unroll
        for (int t = 0; t < 12; ++t) {
            float s0 = sd[t * 7 + n0], s1 = sd[t * 7 + n1], s2 = sd[t * 7 + n2];
            float pb = g[t] * ginv
                     * (d0 * s0 + (1.0f - d0) * (1.0f - s0))
                     * (d1 * s1 + (1.0f - d1) * (1.0f - s1))
                     * (d2 * s2 + (1.0f - d2) * (1.0f - s2));
            rt[tk][t * 8 + l] = f2b(pb);
        }
    }
    __syncthreads();

    // ------------------------------------------------------------------
    // phase 2: out GEMM.  Each wave owns 768 columns (48 16-col tiles) of
    // the 3072-wide (3 heads x 1024) output; every 16-tile lies within one
    // head (all boundaries are multiples of 16).
    // A-frags (routed tokens) come from LDS once; B from lot (L2-hot).
    // ------------------------------------------------------------------
    {
        short8 a0[3], a1[3];
#pragma unroll
        for (int kk = 0; kk < 3; ++kk) {
            a0[kk] = *(const short8*)(&rt[lrow][quad * 8 + kk * 32]);
            a1[kk] = *(const short8*)(&rt[16 + lrow][quad * 8 + kk * 32]);
        }
#pragma unroll 4
        for (int nt = 0; nt < 48; ++nt) {
            int c = wave * 768 + nt * 16;
            int h = c >> 10;
            int d = (c & 1023) + lrow;
            const ushort* bp = lot + (size_t)h * LOT_H + (size_t)d * NJ + quad * 8;
            floatx4 c0 = (floatx4)(0.0f), c1 = (floatx4)(0.0f);
#pragma unroll
            for (int kk = 0; kk < 3; ++kk) {
                short8 b = *(const short8*)(bp + kk * 32);
                c0 = __builtin_amdgcn_mfma_f32_16x16x32_bf16(a0[kk], b, c0, 0, 0, 0);
                c1 = __builtin_amdgcn_mfma_f32_16x16x32_bf16(a1[kk], b, c1, 0, 0, 0);
            }
            float* ob = out + ((size_t)h * NTOK + tb) * DOUT + d;
#pragma unroll
            for (int r = 0; r < 4; ++r) {
                __builtin_nontemporal_store(c0[r], ob + (size_t)(quad * 4 + r) * DOUT);
                __builtin_nontemporal_store(c1[r], ob + (size_t)(16 + quad * 4 + r) * DOUT);
            }
        }
    }
}

// ---------------------------------------------------------------------------
extern "C" void kernel_launch(void* const* d_in, const int* in_sizes, int n_in,
                              void* d_out, int out_size, void* d_ws, size_t ws_size,
                              hipStream_t stream) {
    const float* x   = (const float*)d_in[0];
    const float* dw  = (const float*)d_in[1];
    const float* db  = (const float*)d_in[2];
    const float* ntl = (const float*)d_in[3];
    const float* gw  = (const float*)d_in[4];
    const float* gb  = (const float*)d_in[5];
    const float* lo  = (const float*)d_in[6];
    const int*   pi  = (const int*)d_in[7];
    const float* pd  = (const float*)d_in[8];
    float* out = (float*)d_out;

    ushort* lot  = (ushort*)d_ws;                 // 3*98304*2 = 0.59 MB
    ushort* wcat = lot + (size_t)3 * LOT_H;       // 96*1024*2 = 0.20 MB

    k_prep<<<dim3((3 * LOT_H + NJ * DIN) / 256), dim3(256), 0, stream>>>(lo, dw, gw, lot, wcat);
    k_fused<<<dim3(NTOK / TOKPB), dim3(256), 0, stream>>>(x, wcat, db, ntl, gb, pi, pd, lot, out);
}